// Round 4
// baseline (344.261 us; speedup 1.0000x reference)
//
#include <hip/hip_runtime.h>
#include <hip/hip_cooperative_groups.h>

namespace cg = cooperative_groups;

#define ROWS_TOTAL 8192   // 4 * 2048
#define EMB 1024
#define HEAD 64
#define SEQ 2048
#define KSPLIT 8
#define KCHUNK (SEQ / KSPLIT)   // 256, compile-time

typedef __attribute__((ext_vector_type(8))) short short8;   // 8 bf16 = 4 VGPRs
typedef __attribute__((ext_vector_type(4))) float f32x4;

#define MFMA16(a, b, c) __builtin_amdgcn_mfma_f32_16x16x32_bf16((a), (b), (c), 0, 0, 0)

static __device__ __forceinline__ unsigned short f2bf(float f) {
    union { float f; unsigned u; } v; v.f = f;
    unsigned r = v.u + 0x7fff + ((v.u >> 16) & 1);   // RNE
    return (unsigned short)(r >> 16);
}

// ---------------------------------------------------------------------------
// Single cooperative kernel, 4 phases separated by grid.sync():
//  P0: W -> Wt[3][64][1024] bf16 (B-operand layout), LDS transpose, 48 blocks
//  P1: QKV projection: 512 row-tiles, wave w = 3 full-K col-tiles, no LDS
//      reduce. Q written pre-scaled by 0.125*log2(e); V transposed via LDS.
//  P2: MFMA flash attention partials (R3-verified math), tasks = 128 qblk x 8
//  P3: combine k-split partials
// All phases grid-stride so any co-resident grid size works.
// ---------------------------------------------------------------------------
__global__ __launch_bounds__(256, 4) void fused_attn(
    const float* __restrict__ x,
    const float* __restrict__ Wq, const float* __restrict__ bq,
    const float* __restrict__ Wk, const float* __restrict__ bk,
    const float* __restrict__ Wv, const float* __restrict__ bv,
    unsigned short* __restrict__ Wt,
    unsigned short* __restrict__ Qb, unsigned short* __restrict__ Kb,
    unsigned short* __restrict__ Vt,
    float* __restrict__ Opart, float* __restrict__ lpart,
    float* __restrict__ out)
{
    __shared__ union {
        unsigned short tr[64][68];        // P0: 8.7 KB
        unsigned short vlds[64][20];      // P1: 2.5 KB
        unsigned short plds[4][16][72];   // P2: 9.2 KB (stride 144B: aligned b128)
    } sh;

    cg::grid_group grid = cg::this_grid();
    const int bx   = blockIdx.x;
    const int gdim = gridDim.x;
    const int t    = threadIdx.x;
    const int w    = t >> 6;
    const int lane = t & 63;
    const int ln   = lane & 15;
    const int quad = lane >> 4;
    const f32x4 zero = (f32x4){0.f, 0.f, 0.f, 0.f};

    // ---------------- Phase 0: weight transpose+convert (gdim >= 256 > 48)
    if (bx < 48) {
        const int m  = bx >> 4;
        const int k0 = (bx & 15) << 6;
        const float* __restrict__ W = (m == 0) ? Wq : (m == 1) ? Wk : Wv;
        #pragma unroll
        for (int j = 0; j < 4; ++j) {
            int flat = j * 1024 + t * 4;
            int k = flat >> 6, n = flat & 63;
            float4 w4 = *(const float4*)&W[(size_t)(k0 + k) * 64 + n];
            sh.tr[n + 0][k] = f2bf(w4.x); sh.tr[n + 1][k] = f2bf(w4.y);
            sh.tr[n + 2][k] = f2bf(w4.z); sh.tr[n + 3][k] = f2bf(w4.w);
        }
        __syncthreads();
        const int n  = t >> 2;
        const int kc = (t & 3) * 16;
        short8 o0, o1;
        #pragma unroll
        for (int i = 0; i < 8; ++i) {
            o0[i] = (short)sh.tr[n][kc + i];
            o1[i] = (short)sh.tr[n][kc + 8 + i];
        }
        unsigned short* dst = &Wt[((size_t)m * 64 + n) * 1024 + k0 + kc];
        *(short8*)(dst)     = o0;
        *(short8*)(dst + 8) = o1;
    }
    grid.sync();

    // ---------------- Phase 1: QKV projection (512 row-tile tasks)
    for (int g = bx; g < 512; g += gdim) {
        const int m0 = g * 16;
        f32x4 acc[3];
        #pragma unroll
        for (int j = 0; j < 3; ++j) acc[j] = zero;

        const float* __restrict__ xrow = x + (size_t)(m0 + ln) * EMB;
        const unsigned short* __restrict__ wbase =
            Wt + (size_t)(w * 48 + ln) * 1024 + quad * 8;

        #pragma unroll 2
        for (int kc = 0; kc < EMB; kc += 32) {
            float4 a0 = *(const float4*)&xrow[kc + quad * 8];
            float4 a1 = *(const float4*)&xrow[kc + quad * 8 + 4];
            short8 af;
            af[0] = (short)f2bf(a0.x); af[1] = (short)f2bf(a0.y);
            af[2] = (short)f2bf(a0.z); af[3] = (short)f2bf(a0.w);
            af[4] = (short)f2bf(a1.x); af[5] = (short)f2bf(a1.y);
            af[6] = (short)f2bf(a1.z); af[7] = (short)f2bf(a1.w);
            #pragma unroll
            for (int j = 0; j < 3; ++j) {
                short8 bf = *(const short8*)&wbase[(size_t)j * 16 * 1024 + kc];
                acc[j] = MFMA16(af, bf, acc[j]);
            }
        }

        __syncthreads();   // protect sh.vlds against previous loop iteration
        const float qs = 0.125f * 1.44269504f;   // softmax scale * log2(e)
        #pragma unroll
        for (int j = 0; j < 3; ++j) {
            const int tile = w * 3 + j;
            const int mat  = tile >> 2;
            const int d    = (tile & 3) * 16 + ln;
            const float* bp = (mat == 0) ? bq : (mat == 1) ? bk : bv;
            const float bias = bp[d];
            #pragma unroll
            for (int r = 0; r < 4; ++r) {
                float vfull = acc[j][r] + bias;
                int row = m0 + quad * 4 + r;
                if (mat == 0)      Qb[(size_t)row * 64 + d] = f2bf(vfull * qs);
                else if (mat == 1) Kb[(size_t)row * 64 + d] = f2bf(vfull);
                else               sh.vlds[d][quad * 4 + r] = f2bf(vfull);
            }
        }
        __syncthreads();
        {   // coalesced transposed V store: Vt[b][d][s]
            const int b  = m0 >> 11;
            const int s0 = m0 & 2047;
            const int d  = t >> 2;
            const int sq = (t & 3) * 4;
            ushort4 pk = {sh.vlds[d][sq + 0], sh.vlds[d][sq + 1],
                          sh.vlds[d][sq + 2], sh.vlds[d][sq + 3]};
            *(ushort4*)&Vt[((size_t)b * 64 + d) * SEQ + s0 + sq] = pk;
        }
    }
    grid.sync();

    // ---------------- Phase 2: flash attention partials (1024 tasks)
    for (int task = bx; task < 128 * KSPLIT; task += gdim) {
        const int qblk = task >> 3;
        const int c    = task & 7;
        const int q0   = qblk * 64 + w * 16;
        const int b    = q0 >> 11;

        const unsigned short* qbase = Qb + (size_t)(q0 + ln) * 64 + quad * 8;
        short8 qa0 = *(const short8*)(qbase);        // pre-scaled in P1
        short8 qa1 = *(const short8*)(qbase + 32);

        f32x4 O[4];
        #pragma unroll
        for (int j = 0; j < 4; ++j) O[j] = zero;
        float lacc[4] = {0.f, 0.f, 0.f, 0.f};

        const unsigned short* Kbase = Kb + ((size_t)b * SEQ + c * KCHUNK) * 64;
        const unsigned short* Vbase = Vt + (size_t)b * 64 * SEQ + c * KCHUNK;
        unsigned short* P = &sh.plds[w][0][0];

        #pragma unroll 2
        for (int kt = 0; kt < KCHUNK; kt += 64) {
            const unsigned short* kr = Kbase + (size_t)(kt + ln) * 64 + quad * 8;
            short8 kA0 = *(const short8*)(kr);
            short8 kA1 = *(const short8*)(kr + 32);
            short8 kB0 = *(const short8*)(kr + 16 * 64);
            short8 kB1 = *(const short8*)(kr + 16 * 64 + 32);
            short8 kC0 = *(const short8*)(kr + 32 * 64);
            short8 kC1 = *(const short8*)(kr + 32 * 64 + 32);
            short8 kD0 = *(const short8*)(kr + 48 * 64);
            short8 kD1 = *(const short8*)(kr + 48 * 64 + 32);

            f32x4 sA = MFMA16(qa0, kA0, zero); sA = MFMA16(qa1, kA1, sA);
            f32x4 sB = MFMA16(qa0, kB0, zero); sB = MFMA16(qa1, kB1, sB);
            f32x4 sC = MFMA16(qa0, kC0, zero); sC = MFMA16(qa1, kC1, sC);
            f32x4 sD = MFMA16(qa0, kD0, zero); sD = MFMA16(qa1, kD1, sD);

            #pragma unroll
            for (int r = 0; r < 4; ++r) {
                float pA = __builtin_amdgcn_exp2f(sA[r]);
                float pB = __builtin_amdgcn_exp2f(sB[r]);
                float pC = __builtin_amdgcn_exp2f(sC[r]);
                float pD = __builtin_amdgcn_exp2f(sD[r]);
                lacc[r] += (pA + pB) + (pC + pD);
                unsigned short* prow = P + (quad * 4 + r) * 72;
                prow[ln]      = f2bf(pA);
                prow[16 + ln] = f2bf(pB);
                prow[32 + ln] = f2bf(pC);
                prow[48 + ln] = f2bf(pD);
            }
            short8 pa0 = *(const short8*)&sh.plds[w][ln][quad * 8];
            short8 pa1 = *(const short8*)&sh.plds[w][ln][32 + quad * 8];

            #pragma unroll
            for (int j = 0; j < 4; ++j) {
                const unsigned short* vr =
                    Vbase + (size_t)(j * 16 + ln) * SEQ + kt + quad * 8;
                short8 vb0 = *(const short8*)(vr);
                short8 vb1 = *(const short8*)(vr + 32);
                O[j] = MFMA16(pa0, vb0, O[j]);
                O[j] = MFMA16(pa1, vb1, O[j]);
            }
        }

        #pragma unroll
        for (int m = 1; m < 16; m <<= 1) {
            #pragma unroll
            for (int r = 0; r < 4; ++r) lacc[r] += __shfl_xor(lacc[r], m);
        }

        float* __restrict__ ob = Opart + ((size_t)c * ROWS_TOTAL + q0) * 64;
        #pragma unroll
        for (int j = 0; j < 4; ++j)
            #pragma unroll
            for (int r = 0; r < 4; ++r)
                ob[(size_t)(quad * 4 + r) * 64 + j * 16 + ln] = O[j][r];

        if (ln == 0) {
            #pragma unroll
            for (int r = 0; r < 4; ++r)
                lpart[(size_t)c * ROWS_TOTAL + q0 + quad * 4 + r] = lacc[r];
        }
    }
    grid.sync();

    // ---------------- Phase 3: combine partials
    for (int idx = bx * 256 + t; idx < ROWS_TOTAL * HEAD; idx += gdim * 256) {
        const int r = idx >> 6;
        float osum = 0.f, lsum = 0.f;
        #pragma unroll
        for (int c = 0; c < KSPLIT; ++c) {
            osum += Opart[(size_t)c * ROWS_TOTAL * HEAD + idx];
            lsum += lpart[(size_t)c * ROWS_TOTAL + r];
        }
        out[idx] = osum / lsum;
    }
}

// ---------------------------------------------------------------------------
extern "C" void kernel_launch(void* const* d_in, const int* in_sizes, int n_in,
                              void* d_out, int out_size, void* d_ws, size_t ws_size,
                              hipStream_t stream)
{
    const float* x  = (const float*)d_in[0];
    const float* Wq = (const float*)d_in[1];
    const float* bq = (const float*)d_in[2];
    const float* Wk = (const float*)d_in[3];
    const float* bk = (const float*)d_in[4];
    const float* Wv = (const float*)d_in[5];
    const float* bv = (const float*)d_in[6];
    float* out = (float*)d_out;

    char* ws = (char*)d_ws;
    unsigned short* Qb = (unsigned short*)ws;                       // 1 MB
    unsigned short* Kb = Qb + (size_t)ROWS_TOTAL * HEAD;            // 1 MB
    unsigned short* Vt = Kb + (size_t)ROWS_TOTAL * HEAD;            // 1 MB
    unsigned short* Wt = Vt + (size_t)ROWS_TOTAL * HEAD;            // 384 KB
    float* lpart = (float*)(Wt + (size_t)3 * HEAD * EMB);           // 256 KB
    float* Opart = lpart + (size_t)KSPLIT * ROWS_TOTAL;             // 16 MB

    // co-residency-safe grid: query occupancy (host-side, capture-safe)
    int maxb = 2;
    if (hipOccupancyMaxActiveBlocksPerMultiprocessor(&maxb, fused_attn, 256, 0)
            != hipSuccess || maxb < 1) maxb = 1;
    int grid = maxb * 256;
    if (grid > 1024) grid = 1024;

    void* args[] = {
        (void*)&x, (void*)&Wq, (void*)&bq, (void*)&Wk, (void*)&bk,
        (void*)&Wv, (void*)&bv, (void*)&Wt, (void*)&Qb, (void*)&Kb,
        (void*)&Vt, (void*)&Opart, (void*)&lpart, (void*)&out };
    hipLaunchCooperativeKernel(fused_attn, dim3(grid), dim3(256), args, 0, stream);
}

// Round 5
// 150.311 us; speedup vs baseline: 2.2903x; 2.2903x over previous
//
#include <hip/hip_runtime.h>

#define ROWS_TOTAL 8192   // 4 * 2048
#define EMB 1024
#define HEAD 64
#define SEQ 2048
#define NWAVE 8                 // k-split waves per attn block
#define KCHUNK (SEQ / NWAVE)    // 256, compile-time

typedef __attribute__((ext_vector_type(8))) short short8;   // 8 bf16 = 4 VGPRs
typedef __attribute__((ext_vector_type(4))) float f32x4;

#define MFMA16(a, b, c) __builtin_amdgcn_mfma_f32_16x16x32_bf16((a), (b), (c), 0, 0, 0)

static __device__ __forceinline__ unsigned short f2bf(float f) {
    union { float f; unsigned u; } v; v.f = f;
    unsigned r = v.u + 0x7fff + ((v.u >> 16) & 1);   // RNE
    return (unsigned short)(r >> 16);
}

// ---------------------------------------------------------------------------
// Kernel 0: W[1024][64] -> Wt[3][64][1024] bf16 (B-operand layout), LDS
// transpose for coalesced 16B stores. grid = (16 k-slabs, 3 mats) x 256.
// ---------------------------------------------------------------------------
__global__ __launch_bounds__(256) void wprep_kernel(
    const float* __restrict__ Wq, const float* __restrict__ Wk,
    const float* __restrict__ Wv, unsigned short* __restrict__ Wt)
{
    __shared__ float Tr[64][65];
    const int m  = blockIdx.y;
    const int k0 = blockIdx.x * 64;
    const float* __restrict__ W = (m == 0) ? Wq : (m == 1) ? Wk : Wv;
    const int t = threadIdx.x;

    #pragma unroll
    for (int j = 0; j < 4; ++j) {
        int flat = j * 1024 + t * 4;          // 0..4095
        int k = flat >> 6, n = flat & 63;
        float4 w4 = *(const float4*)&W[(size_t)(k0 + k) * 64 + n];
        Tr[n + 0][k] = w4.x; Tr[n + 1][k] = w4.y;
        Tr[n + 2][k] = w4.z; Tr[n + 3][k] = w4.w;
    }
    __syncthreads();

    const int n  = t >> 2;
    const int kc = (t & 3) * 16;
    short8 o0, o1;
    #pragma unroll
    for (int i = 0; i < 8; ++i) {
        o0[i] = (short)f2bf(Tr[n][kc + i]);
        o1[i] = (short)f2bf(Tr[n][kc + 8 + i]);
    }
    unsigned short* dst = &Wt[((size_t)m * 64 + n) * 1024 + k0 + kc];
    *(short8*)(dst)     = o0;
    *(short8*)(dst + 8) = o1;
}

// ---------------------------------------------------------------------------
// Kernel 1: QKV projection (R4-phase1 design, standalone; verified correct).
// Block = 256 (4 waves), grid = 512. Wave w computes col-tiles w*3..w*3+2
// over the FULL K=1024 (no partials, no LDS reduce). All waves read the same
// 16 X rows (L1-served after first wave). Q written pre-scaled by
// 0.125*log2(e); V transposed through small LDS for coalesced Vt stores.
// ---------------------------------------------------------------------------
__global__ __launch_bounds__(256) void qkv_mfma(
    const float* __restrict__ x, const unsigned short* __restrict__ Wt,
    const float* __restrict__ bq, const float* __restrict__ bk,
    const float* __restrict__ bv,
    unsigned short* __restrict__ Qb, unsigned short* __restrict__ Kb,
    unsigned short* __restrict__ Vt)
{
    __shared__ unsigned short vlds[64][20];

    const int t    = threadIdx.x;
    const int w    = t >> 6;
    const int lane = t & 63;
    const int ln   = lane & 15;
    const int quad = lane >> 4;
    const int m0   = blockIdx.x * 16;

    const f32x4 zero = (f32x4){0.f, 0.f, 0.f, 0.f};
    f32x4 acc[3];
    #pragma unroll
    for (int j = 0; j < 3; ++j) acc[j] = zero;

    const float* __restrict__ xrow = x + (size_t)(m0 + ln) * EMB;
    const unsigned short* __restrict__ wbase =
        Wt + (size_t)(w * 48 + ln) * 1024 + quad * 8;

    #pragma unroll 2
    for (int kc = 0; kc < EMB; kc += 32) {
        float4 a0 = *(const float4*)&xrow[kc + quad * 8];
        float4 a1 = *(const float4*)&xrow[kc + quad * 8 + 4];
        short8 af;
        af[0] = (short)f2bf(a0.x); af[1] = (short)f2bf(a0.y);
        af[2] = (short)f2bf(a0.z); af[3] = (short)f2bf(a0.w);
        af[4] = (short)f2bf(a1.x); af[5] = (short)f2bf(a1.y);
        af[6] = (short)f2bf(a1.z); af[7] = (short)f2bf(a1.w);
        #pragma unroll
        for (int j = 0; j < 3; ++j) {
            short8 bf = *(const short8*)&wbase[(size_t)j * 16 * 1024 + kc];
            acc[j] = MFMA16(af, bf, acc[j]);
        }
    }

    const float qs = 0.125f * 1.44269504f;   // softmax scale * log2(e)
    #pragma unroll
    for (int j = 0; j < 3; ++j) {
        const int tile = w * 3 + j;
        const int mat  = tile >> 2;
        const int d    = (tile & 3) * 16 + ln;
        const float* bp = (mat == 0) ? bq : (mat == 1) ? bk : bv;
        const float bias = bp[d];
        #pragma unroll
        for (int r = 0; r < 4; ++r) {
            float vfull = acc[j][r] + bias;
            int row = m0 + quad * 4 + r;
            if (mat == 0)      Qb[(size_t)row * 64 + d] = f2bf(vfull * qs);
            else if (mat == 1) Kb[(size_t)row * 64 + d] = f2bf(vfull);
            else               vlds[d][quad * 4 + r] = f2bf(vfull);
        }
    }
    __syncthreads();
    {   // coalesced transposed V store: Vt[b][d][s]
        const int b  = m0 >> 11;
        const int s0 = m0 & 2047;
        const int d  = t >> 2;
        const int sq = (t & 3) * 4;
        ushort4 pk = {vlds[d][sq + 0], vlds[d][sq + 1],
                      vlds[d][sq + 2], vlds[d][sq + 3]};
        *(ushort4*)&Vt[((size_t)b * 64 + d) * SEQ + s0 + sq] = pk;
    }
}

// ---------------------------------------------------------------------------
// Kernel 2: MFMA flash attention with IN-BLOCK k-split reduce.
// Block = 512 (8 waves), grid = 512 (one block per 16 q-rows). Wave w owns
// key-chunk [w*256, w*256+256) with the R3-verified inner loop (64 keys/iter,
// exp2 softmax on pre-scaled Q, P through per-wave LDS). Partial O and l are
// combined in LDS and the final out = sum(O)/sum(l) is written directly —
// no Opart/lpart global traffic, no reduce kernel.
// ---------------------------------------------------------------------------
__global__ __launch_bounds__(512) void attn_mfma(
    const unsigned short* __restrict__ Qb, const unsigned short* __restrict__ Kb,
    const unsigned short* __restrict__ Vt,
    float* __restrict__ out)
{
    __shared__ float          Olds[NWAVE][16][66];   // 33.8 KB partial O tiles
    __shared__ unsigned short Plds[NWAVE][16][72];   // 18.4 KB P staging
    __shared__ float          llds[NWAVE][16];       // partial denominators

    const int t    = threadIdx.x;
    const int w    = t >> 6;          // wave = key-chunk index c
    const int lane = t & 63;
    const int ln   = lane & 15;
    const int quad = lane >> 4;

    const int q0 = blockIdx.x * 16;
    const int b  = q0 >> 11;

    const unsigned short* qbase = Qb + (size_t)(q0 + ln) * 64 + quad * 8;
    short8 qa0 = *(const short8*)(qbase);        // pre-scaled in qkv
    short8 qa1 = *(const short8*)(qbase + 32);

    const f32x4 zero = (f32x4){0.f, 0.f, 0.f, 0.f};
    f32x4 O[4];
    #pragma unroll
    for (int j = 0; j < 4; ++j) O[j] = zero;
    float lacc[4] = {0.f, 0.f, 0.f, 0.f};

    const unsigned short* Kbase = Kb + ((size_t)b * SEQ + w * KCHUNK) * 64;
    const unsigned short* Vbase = Vt + (size_t)b * 64 * SEQ + w * KCHUNK;
    unsigned short* P = &Plds[w][0][0];

    #pragma unroll 2
    for (int kt = 0; kt < KCHUNK; kt += 64) {
        const unsigned short* kr = Kbase + (size_t)(kt + ln) * 64 + quad * 8;
        short8 kA0 = *(const short8*)(kr);
        short8 kA1 = *(const short8*)(kr + 32);
        short8 kB0 = *(const short8*)(kr + 16 * 64);
        short8 kB1 = *(const short8*)(kr + 16 * 64 + 32);
        short8 kC0 = *(const short8*)(kr + 32 * 64);
        short8 kC1 = *(const short8*)(kr + 32 * 64 + 32);
        short8 kD0 = *(const short8*)(kr + 48 * 64);
        short8 kD1 = *(const short8*)(kr + 48 * 64 + 32);

        f32x4 sA = MFMA16(qa0, kA0, zero); sA = MFMA16(qa1, kA1, sA);
        f32x4 sB = MFMA16(qa0, kB0, zero); sB = MFMA16(qa1, kB1, sB);
        f32x4 sC = MFMA16(qa0, kC0, zero); sC = MFMA16(qa1, kC1, sC);
        f32x4 sD = MFMA16(qa0, kD0, zero); sD = MFMA16(qa1, kD1, sD);

        #pragma unroll
        for (int r = 0; r < 4; ++r) {
            float pA = __builtin_amdgcn_exp2f(sA[r]);
            float pB = __builtin_amdgcn_exp2f(sB[r]);
            float pC = __builtin_amdgcn_exp2f(sC[r]);
            float pD = __builtin_amdgcn_exp2f(sD[r]);
            lacc[r] += (pA + pB) + (pC + pD);
            unsigned short* prow = P + (quad * 4 + r) * 72;
            prow[ln]      = f2bf(pA);
            prow[16 + ln] = f2bf(pB);
            prow[32 + ln] = f2bf(pC);
            prow[48 + ln] = f2bf(pD);
        }
        short8 pa0 = *(const short8*)&Plds[w][ln][quad * 8];
        short8 pa1 = *(const short8*)&Plds[w][ln][32 + quad * 8];

        #pragma unroll
        for (int j = 0; j < 4; ++j) {
            const unsigned short* vr =
                Vbase + (size_t)(j * 16 + ln) * SEQ + kt + quad * 8;
            short8 vb0 = *(const short8*)(vr);
            short8 vb1 = *(const short8*)(vr + 32);
            O[j] = MFMA16(pa0, vb0, O[j]);
            O[j] = MFMA16(pa1, vb1, O[j]);
        }
    }

    // per-wave denominator: reduce across the 16 columns of the C tile
    #pragma unroll
    for (int m = 1; m < 16; m <<= 1) {
        #pragma unroll
        for (int r = 0; r < 4; ++r) lacc[r] += __shfl_xor(lacc[r], m);
    }

    // stash this wave's partial O tile + l into LDS
    #pragma unroll
    for (int j = 0; j < 4; ++j)
        #pragma unroll
        for (int r = 0; r < 4; ++r)
            Olds[w][quad * 4 + r][j * 16 + ln] = O[j][r];
    if (ln == 0) {
        #pragma unroll
        for (int r = 0; r < 4; ++r) llds[w][quad * 4 + r] = lacc[r];
    }
    __syncthreads();

    // combine 8 partials and write final output (2 elements per thread, 8B)
    {
        const int idx = t * 2;            // 0..1022 over 16x64 tile
        const int row = idx >> 6;
        const int d   = idx & 63;
        float lsum = 0.f, o0 = 0.f, o1 = 0.f;
        #pragma unroll
        for (int v = 0; v < NWAVE; ++v) {
            lsum += llds[v][row];
            o0   += Olds[v][row][d];
            o1   += Olds[v][row][d + 1];
        }
        float inv = 1.0f / lsum;
        float2 res = {o0 * inv, o1 * inv};
        *(float2*)&out[(size_t)(q0 + row) * 64 + d] = res;
    }
}

// ---------------------------------------------------------------------------
extern "C" void kernel_launch(void* const* d_in, const int* in_sizes, int n_in,
                              void* d_out, int out_size, void* d_ws, size_t ws_size,
                              hipStream_t stream)
{
    const float* x  = (const float*)d_in[0];
    const float* Wq = (const float*)d_in[1];
    const float* bq = (const float*)d_in[2];
    const float* Wk = (const float*)d_in[3];
    const float* bk = (const float*)d_in[4];
    const float* Wv = (const float*)d_in[5];
    const float* bv = (const float*)d_in[6];
    float* out = (float*)d_out;

    char* ws = (char*)d_ws;
    unsigned short* Qb = (unsigned short*)ws;                       // 1 MB
    unsigned short* Kb = Qb + (size_t)ROWS_TOTAL * HEAD;            // 1 MB
    unsigned short* Vt = Kb + (size_t)ROWS_TOTAL * HEAD;            // 1 MB
    unsigned short* Wt = Vt + (size_t)ROWS_TOTAL * HEAD;            // 384 KB

    wprep_kernel<<<dim3(16, 3), 256, 0, stream>>>(Wq, Wk, Wv, Wt);
    qkv_mfma<<<dim3(512), 256, 0, stream>>>(x, Wt, bq, bk, bv, Qb, Kb, Vt);
    attn_mfma<<<dim3(512), 512, 0, stream>>>(Qb, Kb, Vt, out);
}

// Round 6
// 147.716 us; speedup vs baseline: 2.3306x; 1.0176x over previous
//
#include <hip/hip_runtime.h>
#include <hip/hip_bf16.h>

#define ROWS_TOTAL 8192   // 4 * 2048
#define EMB 1024
#define HEAD 64
#define SEQ 2048
#define NWAVE 8                 // k-split waves per attn block
#define KCHUNK (SEQ / NWAVE)    // 256, compile-time

typedef __attribute__((ext_vector_type(8))) short short8;   // 8 bf16 = 4 VGPRs
typedef __attribute__((ext_vector_type(4))) float f32x4;

#define MFMA16(a, b, c) __builtin_amdgcn_mfma_f32_16x16x32_bf16((a), (b), (c), 0, 0, 0)

static __device__ __forceinline__ unsigned short f2bf(float f) {
    union { float f; unsigned u; } v; v.f = f;
    unsigned r = v.u + 0x7fff + ((v.u >> 16) & 1);   // RNE
    return (unsigned short)(r >> 16);
}

// packed f32x2 -> bf16x2 (v_cvt_pk_bf16_f32 on gfx950): low16 = a, high16 = b
static __device__ __forceinline__ unsigned pk2(float a, float b) {
    __hip_bfloat162 h = __float22bfloat162_rn(float2{a, b});
    union { __hip_bfloat162 h; unsigned u; } v; v.h = h;
    return v.u;
}

// ---------------------------------------------------------------------------
// Kernel 0: W[1024][64] -> Wt[3][64][1024] bf16 (B-operand layout), LDS
// transpose for coalesced 16B stores. grid = (16 k-slabs, 3 mats) x 256.
// ---------------------------------------------------------------------------
__global__ __launch_bounds__(256) void wprep_kernel(
    const float* __restrict__ Wq, const float* __restrict__ Wk,
    const float* __restrict__ Wv, unsigned short* __restrict__ Wt)
{
    __shared__ float Tr[64][65];
    const int m  = blockIdx.y;
    const int k0 = blockIdx.x * 64;
    const float* __restrict__ W = (m == 0) ? Wq : (m == 1) ? Wk : Wv;
    const int t = threadIdx.x;

    #pragma unroll
    for (int j = 0; j < 4; ++j) {
        int flat = j * 1024 + t * 4;          // 0..4095
        int k = flat >> 6, n = flat & 63;
        float4 w4 = *(const float4*)&W[(size_t)(k0 + k) * 64 + n];
        Tr[n + 0][k] = w4.x; Tr[n + 1][k] = w4.y;
        Tr[n + 2][k] = w4.z; Tr[n + 3][k] = w4.w;
    }
    __syncthreads();

    const int n  = t >> 2;
    const int kc = (t & 3) * 16;
    union { short8 s; unsigned u[4]; } o0, o1;
    #pragma unroll
    for (int i = 0; i < 4; ++i) {
        o0.u[i] = pk2(Tr[n][kc + 2 * i],     Tr[n][kc + 2 * i + 1]);
        o1.u[i] = pk2(Tr[n][kc + 8 + 2 * i], Tr[n][kc + 9 + 2 * i]);
    }
    unsigned short* dst = &Wt[((size_t)m * 64 + n) * 1024 + k0 + kc];
    *(short8*)(dst)     = o0.s;
    *(short8*)(dst + 8) = o1.s;
}

// ---------------------------------------------------------------------------
// Kernel 1: QKV projection. Block = 512 (8 waves), grid = 512.
// Wave w = (col-group cg = w>>1, K-half kh = w&1): computes col-tiles
// cg*3..cg*3+2 over K-half [kh*512, kh*512+512). Odd-half partials are
// pair-reduced through 12 KB LDS. 4096 waves total (2x R5 occupancy),
// 16 k-iterations per wave (half the dependent-chain length).
// Q written pre-scaled by 0.125*log2(e); V transposed via LDS.
// ---------------------------------------------------------------------------
__global__ __launch_bounds__(512) void qkv_mfma(
    const float* __restrict__ x, const unsigned short* __restrict__ Wt,
    const float* __restrict__ bq, const float* __restrict__ bk,
    const float* __restrict__ bv,
    unsigned short* __restrict__ Qb, unsigned short* __restrict__ Kb,
    unsigned short* __restrict__ Vt)
{
    __shared__ f32x4 pr[4][3][64];             // 12 KB odd-half partials
    __shared__ unsigned short vlds[64][20];

    const int t    = threadIdx.x;
    const int w    = t >> 6;
    const int lane = t & 63;
    const int ln   = lane & 15;
    const int quad = lane >> 4;
    const int m0   = blockIdx.x * 16;
    const int cg   = w >> 1;                   // col group 0..3
    const int kh   = w & 1;                    // K half

    const f32x4 zero = (f32x4){0.f, 0.f, 0.f, 0.f};
    f32x4 acc[3];
    #pragma unroll
    for (int j = 0; j < 3; ++j) acc[j] = zero;

    const float* __restrict__ xrow = x + (size_t)(m0 + ln) * EMB + kh * 512;
    const unsigned short* __restrict__ wbase =
        Wt + (size_t)(cg * 48 + ln) * 1024 + kh * 512 + quad * 8;

    #pragma unroll 2
    for (int kc = 0; kc < 512; kc += 32) {
        float4 a0 = *(const float4*)&xrow[kc + quad * 8];
        float4 a1 = *(const float4*)&xrow[kc + quad * 8 + 4];
        union { short8 s; unsigned u[4]; } af;
        af.u[0] = pk2(a0.x, a0.y);
        af.u[1] = pk2(a0.z, a0.w);
        af.u[2] = pk2(a1.x, a1.y);
        af.u[3] = pk2(a1.z, a1.w);
        #pragma unroll
        for (int j = 0; j < 3; ++j) {
            short8 bf = *(const short8*)&wbase[(size_t)j * 16 * 1024 + kc];
            acc[j] = MFMA16(af.s, bf, acc[j]);
        }
    }

    if (kh == 1) {
        #pragma unroll
        for (int j = 0; j < 3; ++j) pr[cg][j][lane] = acc[j];
    }
    __syncthreads();

    if (kh == 0) {
        const float qs = 0.125f * 1.44269504f;   // softmax scale * log2(e)
        #pragma unroll
        for (int j = 0; j < 3; ++j) {
            acc[j] += pr[cg][j][lane];
            const int tile = cg * 3 + j;
            const int mat  = tile >> 2;
            const int d    = (tile & 3) * 16 + ln;
            const float* bp = (mat == 0) ? bq : (mat == 1) ? bk : bv;
            const float bias = bp[d];
            #pragma unroll
            for (int r = 0; r < 4; ++r) {
                float vfull = acc[j][r] + bias;
                int row = m0 + quad * 4 + r;
                if (mat == 0)      Qb[(size_t)row * 64 + d] = f2bf(vfull * qs);
                else if (mat == 1) Kb[(size_t)row * 64 + d] = f2bf(vfull);
                else               vlds[d][quad * 4 + r] = f2bf(vfull);
            }
        }
    }
    __syncthreads();

    if (t < 256) {   // coalesced transposed V store: Vt[b][d][s]
        const int b  = m0 >> 11;
        const int s0 = m0 & 2047;
        const int d  = t >> 2;
        const int sq = (t & 3) * 4;
        ushort4 pk = {vlds[d][sq + 0], vlds[d][sq + 1],
                      vlds[d][sq + 2], vlds[d][sq + 3]};
        *(ushort4*)&Vt[((size_t)b * 64 + d) * SEQ + s0 + sq] = pk;
    }
}

// ---------------------------------------------------------------------------
// Kernel 2: MFMA flash attention with IN-BLOCK k-split reduce (R5-verified).
// Block = 512 (8 waves), grid = 512. Wave w owns key-chunk [w*256,+256),
// 64 keys/iter, exp2 softmax on pre-scaled Q, P staged through per-wave LDS
// with packed bf16 converts. Partials combined in LDS; final out written
// directly.
// ---------------------------------------------------------------------------
__global__ __launch_bounds__(512) void attn_mfma(
    const unsigned short* __restrict__ Qb, const unsigned short* __restrict__ Kb,
    const unsigned short* __restrict__ Vt,
    float* __restrict__ out)
{
    __shared__ float          Olds[NWAVE][16][66];   // 33.8 KB partial O tiles
    __shared__ unsigned short Plds[NWAVE][16][72];   // 18.4 KB P staging
    __shared__ float          llds[NWAVE][16];       // partial denominators

    const int t    = threadIdx.x;
    const int w    = t >> 6;          // wave = key-chunk index c
    const int lane = t & 63;
    const int ln   = lane & 15;
    const int quad = lane >> 4;

    const int q0 = blockIdx.x * 16;
    const int b  = q0 >> 11;

    const unsigned short* qbase = Qb + (size_t)(q0 + ln) * 64 + quad * 8;
    short8 qa0 = *(const short8*)(qbase);        // pre-scaled in qkv
    short8 qa1 = *(const short8*)(qbase + 32);

    const f32x4 zero = (f32x4){0.f, 0.f, 0.f, 0.f};
    f32x4 O[4];
    #pragma unroll
    for (int j = 0; j < 4; ++j) O[j] = zero;
    float lacc[4] = {0.f, 0.f, 0.f, 0.f};

    const unsigned short* Kbase = Kb + ((size_t)b * SEQ + w * KCHUNK) * 64;
    const unsigned short* Vbase = Vt + (size_t)b * 64 * SEQ + w * KCHUNK;
    unsigned short* P = &Plds[w][0][0];

    #pragma unroll 2
    for (int kt = 0; kt < KCHUNK; kt += 64) {
        const unsigned short* kr = Kbase + (size_t)(kt + ln) * 64 + quad * 8;
        short8 kA0 = *(const short8*)(kr);
        short8 kA1 = *(const short8*)(kr + 32);
        short8 kB0 = *(const short8*)(kr + 16 * 64);
        short8 kB1 = *(const short8*)(kr + 16 * 64 + 32);
        short8 kC0 = *(const short8*)(kr + 32 * 64);
        short8 kC1 = *(const short8*)(kr + 32 * 64 + 32);
        short8 kD0 = *(const short8*)(kr + 48 * 64);
        short8 kD1 = *(const short8*)(kr + 48 * 64 + 32);

        f32x4 sA = MFMA16(qa0, kA0, zero); sA = MFMA16(qa1, kA1, sA);
        f32x4 sB = MFMA16(qa0, kB0, zero); sB = MFMA16(qa1, kB1, sB);
        f32x4 sC = MFMA16(qa0, kC0, zero); sC = MFMA16(qa1, kC1, sC);
        f32x4 sD = MFMA16(qa0, kD0, zero); sD = MFMA16(qa1, kD1, sD);

        #pragma unroll
        for (int r = 0; r < 4; ++r) {
            float pA = __builtin_amdgcn_exp2f(sA[r]);
            float pB = __builtin_amdgcn_exp2f(sB[r]);
            float pC = __builtin_amdgcn_exp2f(sC[r]);
            float pD = __builtin_amdgcn_exp2f(sD[r]);
            lacc[r] += (pA + pB) + (pC + pD);
            unsigned uAB = pk2(pA, pB);
            unsigned uCD = pk2(pC, pD);
            unsigned short* prow = P + (quad * 4 + r) * 72;
            prow[ln]      = (unsigned short)uAB;
            prow[16 + ln] = (unsigned short)(uAB >> 16);
            prow[32 + ln] = (unsigned short)uCD;
            prow[48 + ln] = (unsigned short)(uCD >> 16);
        }
        short8 pa0 = *(const short8*)&Plds[w][ln][quad * 8];
        short8 pa1 = *(const short8*)&Plds[w][ln][32 + quad * 8];

        #pragma unroll
        for (int j = 0; j < 4; ++j) {
            const unsigned short* vr =
                Vbase + (size_t)(j * 16 + ln) * SEQ + kt + quad * 8;
            short8 vb0 = *(const short8*)(vr);
            short8 vb1 = *(const short8*)(vr + 32);
            O[j] = MFMA16(pa0, vb0, O[j]);
            O[j] = MFMA16(pa1, vb1, O[j]);
        }
    }

    // per-wave denominator: reduce across the 16 columns of the C tile
    #pragma unroll
    for (int m = 1; m < 16; m <<= 1) {
        #pragma unroll
        for (int r = 0; r < 4; ++r) lacc[r] += __shfl_xor(lacc[r], m);
    }

    // stash this wave's partial O tile + l into LDS
    #pragma unroll
    for (int j = 0; j < 4; ++j)
        #pragma unroll
        for (int r = 0; r < 4; ++r)
            Olds[w][quad * 4 + r][j * 16 + ln] = O[j][r];
    if (ln == 0) {
        #pragma unroll
        for (int r = 0; r < 4; ++r) llds[w][quad * 4 + r] = lacc[r];
    }
    __syncthreads();

    // combine 8 partials and write final output (2 elements per thread, 8B)
    {
        const int idx = t * 2;            // 0..1022 over 16x64 tile
        const int row = idx >> 6;
        const int d   = idx & 63;
        float lsum = 0.f, o0 = 0.f, o1 = 0.f;
        #pragma unroll
        for (int v = 0; v < NWAVE; ++v) {
            lsum += llds[v][row];
            o0   += Olds[v][row][d];
            o1   += Olds[v][row][d + 1];
        }
        float inv = 1.0f / lsum;
        float2 res = {o0 * inv, o1 * inv};
        *(float2*)&out[(size_t)(q0 + row) * 64 + d] = res;
    }
}

// ---------------------------------------------------------------------------
extern "C" void kernel_launch(void* const* d_in, const int* in_sizes, int n_in,
                              void* d_out, int out_size, void* d_ws, size_t ws_size,
                              hipStream_t stream)
{
    const float* x  = (const float*)d_in[0];
    const float* Wq = (const float*)d_in[1];
    const float* bq = (const float*)d_in[2];
    const float* Wk = (const float*)d_in[3];
    const float* bk = (const float*)d_in[4];
    const float* Wv = (const float*)d_in[5];
    const float* bv = (const float*)d_in[6];
    float* out = (float*)d_out;

    char* ws = (char*)d_ws;
    unsigned short* Qb = (unsigned short*)ws;                       // 1 MB
    unsigned short* Kb = Qb + (size_t)ROWS_TOTAL * HEAD;            // 1 MB
    unsigned short* Vt = Kb + (size_t)ROWS_TOTAL * HEAD;            // 1 MB
    unsigned short* Wt = Vt + (size_t)ROWS_TOTAL * HEAD;            // 384 KB

    wprep_kernel<<<dim3(16, 3), 256, 0, stream>>>(Wq, Wk, Wv, Wt);
    qkv_mfma<<<dim3(512), 512, 0, stream>>>(x, Wt, bq, bk, bv, Qb, Kb, Vt);
    attn_mfma<<<dim3(512), 512, 0, stream>>>(Qb, Kb, Vt, out);
}

// Round 7
// 134.892 us; speedup vs baseline: 2.5521x; 1.0951x over previous
//
#include <hip/hip_runtime.h>
#include <hip/hip_bf16.h>

#define ROWS_TOTAL 8192   // 4 * 2048
#define EMB 1024
#define HEAD 64
#define SEQ 2048
#define KSPLIT 8                // k-chunks (blockIdx.y)
#define KC (SEQ / KSPLIT)       // 256 keys per block
#define KT 64                   // keys per staged tile

typedef __attribute__((ext_vector_type(8))) short short8;   // 8 bf16 = 4 VGPRs
typedef __attribute__((ext_vector_type(4))) float f32x4;

#define MFMA16(a, b, c) __builtin_amdgcn_mfma_f32_16x16x32_bf16((a), (b), (c), 0, 0, 0)

static __device__ __forceinline__ unsigned short f2bf(float f) {
    union { float f; unsigned u; } v; v.f = f;
    unsigned r = v.u + 0x7fff + ((v.u >> 16) & 1);   // RNE
    return (unsigned short)(r >> 16);
}

// packed f32x2 -> bf16x2 (v_cvt_pk_bf16_f32 on gfx950): low16 = a, high16 = b
static __device__ __forceinline__ unsigned pk2(float a, float b) {
    __hip_bfloat162 h = __float22bfloat162_rn(float2{a, b});
    union { __hip_bfloat162 h; unsigned u; } v; v.h = h;
    return v.u;
}

// ---------------------------------------------------------------------------
// Kernel 0: W[1024][64] -> Wt[3][64][1024] bf16 (B-operand layout), LDS
// transpose for coalesced 16B stores. grid = (16 k-slabs, 3 mats) x 256.
// (R6-verified, unchanged.)
// ---------------------------------------------------------------------------
__global__ __launch_bounds__(256) void wprep_kernel(
    const float* __restrict__ Wq, const float* __restrict__ Wk,
    const float* __restrict__ Wv, unsigned short* __restrict__ Wt)
{
    __shared__ float Tr[64][65];
    const int m  = blockIdx.y;
    const int k0 = blockIdx.x * 64;
    const float* __restrict__ W = (m == 0) ? Wq : (m == 1) ? Wk : Wv;
    const int t = threadIdx.x;

    #pragma unroll
    for (int j = 0; j < 4; ++j) {
        int flat = j * 1024 + t * 4;          // 0..4095
        int k = flat >> 6, n = flat & 63;
        float4 w4 = *(const float4*)&W[(size_t)(k0 + k) * 64 + n];
        Tr[n + 0][k] = w4.x; Tr[n + 1][k] = w4.y;
        Tr[n + 2][k] = w4.z; Tr[n + 3][k] = w4.w;
    }
    __syncthreads();

    const int n  = t >> 2;
    const int kc = (t & 3) * 16;
    union { short8 s; unsigned u[4]; } o0, o1;
    #pragma unroll
    for (int i = 0; i < 4; ++i) {
        o0.u[i] = pk2(Tr[n][kc + 2 * i],     Tr[n][kc + 2 * i + 1]);
        o1.u[i] = pk2(Tr[n][kc + 8 + 2 * i], Tr[n][kc + 9 + 2 * i]);
    }
    unsigned short* dst = &Wt[((size_t)m * 64 + n) * 1024 + k0 + kc];
    *(short8*)(dst)     = o0.s;
    *(short8*)(dst + 8) = o1.s;
}

// ---------------------------------------------------------------------------
// Kernel 1: QKV projection (R6-verified, unchanged). Block = 512 (8 waves),
// grid = 512. Wave w = (col-group, K-half); odd-half partials pair-reduced
// through LDS. Q pre-scaled by 0.125*log2(e); V transposed via LDS.
// ---------------------------------------------------------------------------
__global__ __launch_bounds__(512) void qkv_mfma(
    const float* __restrict__ x, const unsigned short* __restrict__ Wt,
    const float* __restrict__ bq, const float* __restrict__ bk,
    const float* __restrict__ bv,
    unsigned short* __restrict__ Qb, unsigned short* __restrict__ Kb,
    unsigned short* __restrict__ Vt)
{
    __shared__ f32x4 pr[4][3][64];             // 12 KB odd-half partials
    __shared__ unsigned short vlds[64][20];

    const int t    = threadIdx.x;
    const int w    = t >> 6;
    const int lane = t & 63;
    const int ln   = lane & 15;
    const int quad = lane >> 4;
    const int m0   = blockIdx.x * 16;
    const int cg   = w >> 1;                   // col group 0..3
    const int kh   = w & 1;                    // K half

    const f32x4 zero = (f32x4){0.f, 0.f, 0.f, 0.f};
    f32x4 acc[3];
    #pragma unroll
    for (int j = 0; j < 3; ++j) acc[j] = zero;

    const float* __restrict__ xrow = x + (size_t)(m0 + ln) * EMB + kh * 512;
    const unsigned short* __restrict__ wbase =
        Wt + (size_t)(cg * 48 + ln) * 1024 + kh * 512 + quad * 8;

    #pragma unroll 2
    for (int kc = 0; kc < 512; kc += 32) {
        float4 a0 = *(const float4*)&xrow[kc + quad * 8];
        float4 a1 = *(const float4*)&xrow[kc + quad * 8 + 4];
        union { short8 s; unsigned u[4]; } af;
        af.u[0] = pk2(a0.x, a0.y);
        af.u[1] = pk2(a0.z, a0.w);
        af.u[2] = pk2(a1.x, a1.y);
        af.u[3] = pk2(a1.z, a1.w);
        #pragma unroll
        for (int j = 0; j < 3; ++j) {
            short8 bf = *(const short8*)&wbase[(size_t)j * 16 * 1024 + kc];
            acc[j] = MFMA16(af.s, bf, acc[j]);
        }
    }

    if (kh == 1) {
        #pragma unroll
        for (int j = 0; j < 3; ++j) pr[cg][j][lane] = acc[j];
    }
    __syncthreads();

    if (kh == 0) {
        const float qs = 0.125f * 1.44269504f;   // softmax scale * log2(e)
        #pragma unroll
        for (int j = 0; j < 3; ++j) {
            acc[j] += pr[cg][j][lane];
            const int tile = cg * 3 + j;
            const int mat  = tile >> 2;
            const int d    = (tile & 3) * 16 + ln;
            const float* bp = (mat == 0) ? bq : (mat == 1) ? bk : bv;
            const float bias = bp[d];
            #pragma unroll
            for (int r = 0; r < 4; ++r) {
                float vfull = acc[j][r] + bias;
                int row = m0 + quad * 4 + r;
                if (mat == 0)      Qb[(size_t)row * 64 + d] = f2bf(vfull * qs);
                else if (mat == 1) Kb[(size_t)row * 64 + d] = f2bf(vfull);
                else               vlds[d][quad * 4 + r] = f2bf(vfull);
            }
        }
    }
    __syncthreads();

    if (t < 256) {   // coalesced transposed V store: Vt[b][d][s]
        const int b  = m0 >> 11;
        const int s0 = m0 & 2047;
        const int d  = t >> 2;
        const int sq = (t & 3) * 4;
        ushort4 pk = {vlds[d][sq + 0], vlds[d][sq + 1],
                      vlds[d][sq + 2], vlds[d][sq + 3]};
        *(ushort4*)&Vt[((size_t)b * 64 + d) * SEQ + s0 + sq] = pk;
    }
}

// ---------------------------------------------------------------------------
// Kernel 2: MFMA flash attention with BLOCK-COOPERATIVE LDS STAGING.
// grid = (64 q-blocks of 128 rows, 8 k-chunks), block = 512 (8 waves).
// Wave w owns q-rows [q0+w*16, +16); all waves share each staged 64-key
// K/V tile. Staging: 512 threads x one dense 16B chunk each per matrix —
// perfectly coalesced (vs 16-segment scatter per b128 before). Fragments
// via ds_read_b128 at 144B row stride (2-way bank alias = free).
// Partials to Opart/lpart (R3-verified layout), combined by reduce_kernel.
// ---------------------------------------------------------------------------
__global__ __launch_bounds__(512) void attn_mfma(
    const unsigned short* __restrict__ Qb, const unsigned short* __restrict__ Kb,
    const unsigned short* __restrict__ Vt,
    float* __restrict__ Opart, float* __restrict__ lpart)
{
    __shared__ unsigned short Kl[KT][72];        // 9.2 KB  [key][d]
    __shared__ unsigned short Vl[HEAD][72];      // 9.2 KB  [d][key] (V^T)
    __shared__ unsigned short Plds[8][16][72];   // 18.4 KB per-wave P staging

    const int t    = threadIdx.x;
    const int w    = t >> 6;
    const int lane = t & 63;
    const int ln   = lane & 15;
    const int quad = lane >> 4;

    const int c  = blockIdx.y;                   // k-chunk
    const int q0 = blockIdx.x * 128 + w * 16;    // this wave's q-rows
    const int b  = blockIdx.x >> 4;              // batch (128 rows/block)

    // Q A-fragments (pre-scaled in qkv)
    const unsigned short* qbase = Qb + (size_t)(q0 + ln) * 64 + quad * 8;
    short8 qa0 = *(const short8*)(qbase);
    short8 qa1 = *(const short8*)(qbase + 32);

    const f32x4 zero = (f32x4){0.f, 0.f, 0.f, 0.f};
    f32x4 O[4];
    #pragma unroll
    for (int j = 0; j < 4; ++j) O[j] = zero;
    float lacc[4] = {0.f, 0.f, 0.f, 0.f};

    // staging source pointers (dense, coalesced)
    const int skey = t >> 3;             // 0..63
    const int soff = (t & 7) * 8;        // 0..56
    const unsigned short* Ksrc =
        Kb + ((size_t)b * SEQ + c * KC + skey) * 64 + soff;
    const unsigned short* Vsrc =
        Vt + ((size_t)b * 64 + skey) * SEQ + c * KC + soff;

    unsigned short* P = &Plds[w][0][0];

    for (int kt = 0; kt < KC; kt += KT) {
        // ---- cooperative staging: 8 KB K + 8 KB V, one b128 each
        *(short8*)&Kl[skey][soff] = *(const short8*)(Ksrc + (size_t)kt * 64);
        *(short8*)&Vl[skey][soff] = *(const short8*)(Vsrc + kt);
        __syncthreads();

        // ---- QK^T: 4 sub-tiles of 16 keys, fragments from LDS
        f32x4 s[4];
        #pragma unroll
        for (int sub = 0; sub < 4; ++sub) {
            short8 kb0 = *(const short8*)&Kl[sub * 16 + ln][quad * 8];
            short8 kb1 = *(const short8*)&Kl[sub * 16 + ln][32 + quad * 8];
            s[sub] = MFMA16(qa0, kb0, zero);
            s[sub] = MFMA16(qa1, kb1, s[sub]);
        }

        // ---- p = exp2(s); denominator; stage P (C-layout -> A-layout)
        #pragma unroll
        for (int r = 0; r < 4; ++r) {
            float p0 = __builtin_amdgcn_exp2f(s[0][r]);
            float p1 = __builtin_amdgcn_exp2f(s[1][r]);
            float p2 = __builtin_amdgcn_exp2f(s[2][r]);
            float p3 = __builtin_amdgcn_exp2f(s[3][r]);
            lacc[r] += (p0 + p1) + (p2 + p3);
            unsigned u01 = pk2(p0, p1);
            unsigned u23 = pk2(p2, p3);
            unsigned short* prow = P + (quad * 4 + r) * 72;
            prow[ln]      = (unsigned short)u01;
            prow[16 + ln] = (unsigned short)(u01 >> 16);
            prow[32 + ln] = (unsigned short)u23;
            prow[48 + ln] = (unsigned short)(u23 >> 16);
        }
        short8 pa0 = *(const short8*)&Plds[w][ln][quad * 8];
        short8 pa1 = *(const short8*)&Plds[w][ln][32 + quad * 8];

        // ---- PV: fragments from staged V^T
        #pragma unroll
        for (int j = 0; j < 4; ++j) {
            short8 vb0 = *(const short8*)&Vl[j * 16 + ln][quad * 8];
            short8 vb1 = *(const short8*)&Vl[j * 16 + ln][32 + quad * 8];
            O[j] = MFMA16(pa0, vb0, O[j]);
            O[j] = MFMA16(pa1, vb1, O[j]);
        }
        __syncthreads();
    }

    // per-wave denominator: reduce across the 16 key-columns of the C tile
    #pragma unroll
    for (int m = 1; m < 16; m <<= 1) {
        #pragma unroll
        for (int r = 0; r < 4; ++r) lacc[r] += __shfl_xor(lacc[r], m);
    }

    float* __restrict__ ob = Opart + ((size_t)c * ROWS_TOTAL + q0) * 64;
    #pragma unroll
    for (int j = 0; j < 4; ++j)
        #pragma unroll
        for (int r = 0; r < 4; ++r)
            ob[(size_t)(quad * 4 + r) * 64 + j * 16 + ln] = O[j][r];

    if (ln == 0) {
        #pragma unroll
        for (int r = 0; r < 4; ++r)
            lpart[(size_t)c * ROWS_TOTAL + q0 + quad * 4 + r] = lacc[r];
    }
}

// ---------------------------------------------------------------------------
// Kernel 3: combine k-split partials:  out = sum_c O_c / sum_c l_c
// (R3-verified.)
// ---------------------------------------------------------------------------
__global__ __launch_bounds__(256) void reduce_kernel(
    const float* __restrict__ Opart, const float* __restrict__ lpart,
    float* __restrict__ out)
{
    const int idx = blockIdx.x * 256 + threadIdx.x;   // [0, 8192*64)
    const int r   = idx >> 6;
    float osum = 0.f, lsum = 0.f;
    #pragma unroll
    for (int c = 0; c < KSPLIT; ++c) {
        osum += Opart[(size_t)c * ROWS_TOTAL * HEAD + idx];
        lsum += lpart[(size_t)c * ROWS_TOTAL + r];
    }
    out[idx] = osum / lsum;
}

// ---------------------------------------------------------------------------
extern "C" void kernel_launch(void* const* d_in, const int* in_sizes, int n_in,
                              void* d_out, int out_size, void* d_ws, size_t ws_size,
                              hipStream_t stream)
{
    const float* x  = (const float*)d_in[0];
    const float* Wq = (const float*)d_in[1];
    const float* bq = (const float*)d_in[2];
    const float* Wk = (const float*)d_in[3];
    const float* bk = (const float*)d_in[4];
    const float* Wv = (const float*)d_in[5];
    const float* bv = (const float*)d_in[6];
    float* out = (float*)d_out;

    char* ws = (char*)d_ws;
    unsigned short* Qb = (unsigned short*)ws;                       // 1 MB
    unsigned short* Kb = Qb + (size_t)ROWS_TOTAL * HEAD;            // 1 MB
    unsigned short* Vt = Kb + (size_t)ROWS_TOTAL * HEAD;            // 1 MB
    unsigned short* Wt = Vt + (size_t)ROWS_TOTAL * HEAD;            // 384 KB
    float* lpart = (float*)(Wt + (size_t)3 * HEAD * EMB);           // 256 KB
    float* Opart = lpart + (size_t)KSPLIT * ROWS_TOTAL;             // 16 MB

    wprep_kernel<<<dim3(16, 3), 256, 0, stream>>>(Wq, Wk, Wv, Wt);
    qkv_mfma<<<dim3(512), 512, 0, stream>>>(x, Wt, bq, bk, bv, Qb, Kb, Vt);
    attn_mfma<<<dim3(64, KSPLIT), 512, 0, stream>>>(Qb, Kb, Vt, Opart, lpart);
    reduce_kernel<<<dim3((ROWS_TOTAL * HEAD) / 256), 256, 0, stream>>>(Opart, lpart, out);
}

// Round 8
// 118.791 us; speedup vs baseline: 2.8980x; 1.1355x over previous
//
#include <hip/hip_runtime.h>
#include <hip/hip_bf16.h>

#define ROWS_TOTAL 8192   // 4 * 2048
#define EMB 1024
#define HEAD 64
#define SEQ 2048
#define KSPLIT 8                // attn k-chunks (blockIdx.y)
#define KC (SEQ / KSPLIT)       // 256 keys per attn block
#define KT 64                   // keys per staged attn tile

typedef __attribute__((ext_vector_type(8))) short short8;   // 8 bf16 = 4 VGPRs
typedef __attribute__((ext_vector_type(4))) float f32x4;

#define MFMA16(a, b, c) __builtin_amdgcn_mfma_f32_16x16x32_bf16((a), (b), (c), 0, 0, 0)

static __device__ __forceinline__ unsigned short f2bf(float f) {
    union { float f; unsigned u; } v; v.f = f;
    unsigned r = v.u + 0x7fff + ((v.u >> 16) & 1);   // RNE
    return (unsigned short)(r >> 16);
}

// packed f32x2 -> bf16x2 (v_cvt_pk_bf16_f32 on gfx950): low16 = a, high16 = b
static __device__ __forceinline__ unsigned pk2(float a, float b) {
    __hip_bfloat162 h = __float22bfloat162_rn(float2{a, b});
    union { __hip_bfloat162 h; unsigned u; } v; v.h = h;
    return v.u;
}

// ---------------------------------------------------------------------------
// Kernel 0: W[1024][64] x3 -> Wf bf16 in MFMA B-FRAGMENT ORDER:
//   Wf[kc32][tile][ln][quad][8elt], tile = mat*4 + (col>>4), ln = col&15,
//   kc32 = k>>5, quad = (k>>3)&3, elt = k&7.
// A wave's B-fragment load then covers a dense 1 KB region (64 lanes x 16B,
// disjoint) -> full-cacheline coalescing, no 16-segment scatter.
// grid = (16 k-slabs, 3 mats) x 256.
// ---------------------------------------------------------------------------
__global__ __launch_bounds__(256) void wprep_kernel(
    const float* __restrict__ Wq, const float* __restrict__ Wk,
    const float* __restrict__ Wv, unsigned short* __restrict__ Wf)
{
    __shared__ float Tr[64][65];
    const int m  = blockIdx.y;
    const int k0 = blockIdx.x * 64;
    const float* __restrict__ W = (m == 0) ? Wq : (m == 1) ? Wk : Wv;
    const int t = threadIdx.x;

    #pragma unroll
    for (int j = 0; j < 4; ++j) {
        int flat = j * 1024 + t * 4;          // 0..4095
        int k = flat >> 6, n = flat & 63;
        float4 w4 = *(const float4*)&W[(size_t)(k0 + k) * 64 + n];
        Tr[n + 0][k] = w4.x; Tr[n + 1][k] = w4.y;
        Tr[n + 2][k] = w4.z; Tr[n + 3][k] = w4.w;
    }
    __syncthreads();

    const int n   = t >> 2;                   // col 0..63
    const int k16 = t & 3;                    // 16-k chunk within slab
    union { short8 s; unsigned u[4]; } o0, o1;
    #pragma unroll
    for (int i = 0; i < 4; ++i) {
        o0.u[i] = pk2(Tr[n][k16 * 16 + 2 * i],     Tr[n][k16 * 16 + 2 * i + 1]);
        o1.u[i] = pk2(Tr[n][k16 * 16 + 8 + 2 * i], Tr[n][k16 * 16 + 9 + 2 * i]);
    }
    const int tile = m * 4 + (n >> 4);
    const int ln   = n & 15;
    const int kc32 = (k0 >> 5) + (k16 >> 1);
    const int half = k16 & 1;                 // which 16-ushort half of ln-row
    size_t off = ((size_t)(kc32 * 12 + tile) * 16 + ln) * 32 + half * 16;
    *(short8*)&Wf[off]     = o0.s;            // quads 0,1 (or 2,3)
    *(short8*)&Wf[off + 8] = o1.s;
}

// ---------------------------------------------------------------------------
// Kernel 1: QKV projection, coalesced edition. Block = 512 (8 waves),
// grid = 512 (16 rows each). Per 128-k iteration: X tile (16x128 fp32) is
// cooperatively staged (dense float4 loads, cvt_pk -> bf16 LDS); wave
// (cg = w>>1, kh = w&1) computes col-tiles cg*3..+2 for k-subrange
// kh*64..+64, A-frags via ds_read_b128, B-frags as DENSE 1KB global loads
// from fragment-ordered Wf (L2-resident). kh=1 partials pair-reduced via
// LDS. Q pre-scaled by 0.125*log2(e); V transposed via LDS.
// ---------------------------------------------------------------------------
__global__ __launch_bounds__(512) void qkv_mfma(
    const float* __restrict__ x, const unsigned short* __restrict__ Wf,
    const float* __restrict__ bq, const float* __restrict__ bk,
    const float* __restrict__ bv,
    unsigned short* __restrict__ Qb, unsigned short* __restrict__ Kb,
    unsigned short* __restrict__ Vt)
{
    __shared__ unsigned short Xl[16][136];     // 4.25 KB staged X (bf16), 272B rows
    __shared__ f32x4 pr[4][3][64];             // 12 KB kh=1 partials
    __shared__ unsigned short vlds[64][20];

    const int t    = threadIdx.x;
    const int w    = t >> 6;
    const int lane = t & 63;
    const int ln   = lane & 15;
    const int quad = lane >> 4;
    const int m0   = blockIdx.x * 16;
    const int cg   = w >> 1;                   // col group 0..3
    const int kh   = w & 1;                    // k sub-half of each tile

    const f32x4 zero = (f32x4){0.f, 0.f, 0.f, 0.f};
    f32x4 acc[3];
    #pragma unroll
    for (int j = 0; j < 3; ++j) acc[j] = zero;

    // staging map: thread -> (row, 4 floats), coalesced within rows
    const int srow = t >> 5;                   // 0..15
    const int scol = (t & 31) * 4;             // 0..124
    const float* __restrict__ xsrc = x + (size_t)(m0 + srow) * EMB + scol;

    for (int kt = 0; kt < EMB; kt += 128) {
        float4 xv = *(const float4*)(xsrc + kt);
        uint2 pk; pk.x = pk2(xv.x, xv.y); pk.y = pk2(xv.z, xv.w);
        *(uint2*)&Xl[srow][scol] = pk;
        __syncthreads();

        #pragma unroll
        for (int cc = 0; cc < 2; ++cc) {
            short8 af = *(const short8*)&Xl[ln][kh * 64 + cc * 32 + quad * 8];
            const int kc32 = (kt >> 5) + kh * 2 + cc;
            #pragma unroll
            for (int j = 0; j < 3; ++j) {
                const int tile = cg * 3 + j;
                const unsigned short* wp =
                    Wf + ((size_t)(kc32 * 12 + tile) * 16 + ln) * 32 + quad * 8;
                short8 bf = *(const short8*)wp;
                acc[j] = MFMA16(af, bf, acc[j]);
            }
        }
        __syncthreads();
    }

    if (kh == 1) {
        #pragma unroll
        for (int j = 0; j < 3; ++j) pr[cg][j][lane] = acc[j];
    }
    __syncthreads();

    if (kh == 0) {
        const float qs = 0.125f * 1.44269504f;   // softmax scale * log2(e)
        #pragma unroll
        for (int j = 0; j < 3; ++j) {
            acc[j] += pr[cg][j][lane];
            const int tile = cg * 3 + j;
            const int mat  = tile >> 2;
            const int d    = (tile & 3) * 16 + ln;
            const float* bp = (mat == 0) ? bq : (mat == 1) ? bk : bv;
            const float bias = bp[d];
            #pragma unroll
            for (int r = 0; r < 4; ++r) {
                float vfull = acc[j][r] + bias;
                int row = m0 + quad * 4 + r;
                if (mat == 0)      Qb[(size_t)row * 64 + d] = f2bf(vfull * qs);
                else if (mat == 1) Kb[(size_t)row * 64 + d] = f2bf(vfull);
                else               vlds[d][quad * 4 + r] = f2bf(vfull);
            }
        }
    }
    __syncthreads();

    if (t < 256) {   // coalesced transposed V store: Vt[b][d][s]
        const int b  = m0 >> 11;
        const int s0 = m0 & 2047;
        const int d  = t >> 2;
        const int sq = (t & 3) * 4;
        ushort4 pk = {vlds[d][sq + 0], vlds[d][sq + 1],
                      vlds[d][sq + 2], vlds[d][sq + 3]};
        *(ushort4*)&Vt[((size_t)b * 64 + d) * SEQ + s0 + sq] = pk;
    }
}

// ---------------------------------------------------------------------------
// Kernel 2: MFMA flash attention with block-cooperative LDS staging
// (R7-verified, unchanged). grid = (64 q-blocks of 128 rows, 8 k-chunks),
// block = 512 (8 waves).
// ---------------------------------------------------------------------------
__global__ __launch_bounds__(512) void attn_mfma(
    const unsigned short* __restrict__ Qb, const unsigned short* __restrict__ Kb,
    const unsigned short* __restrict__ Vt,
    float* __restrict__ Opart, float* __restrict__ lpart)
{
    __shared__ unsigned short Kl[KT][72];        // 9.2 KB  [key][d]
    __shared__ unsigned short Vl[HEAD][72];      // 9.2 KB  [d][key] (V^T)
    __shared__ unsigned short Plds[8][16][72];   // 18.4 KB per-wave P staging

    const int t    = threadIdx.x;
    const int w    = t >> 6;
    const int lane = t & 63;
    const int ln   = lane & 15;
    const int quad = lane >> 4;

    const int c  = blockIdx.y;                   // k-chunk
    const int q0 = blockIdx.x * 128 + w * 16;    // this wave's q-rows
    const int b  = blockIdx.x >> 4;              // batch (128 rows/block)

    const unsigned short* qbase = Qb + (size_t)(q0 + ln) * 64 + quad * 8;
    short8 qa0 = *(const short8*)(qbase);
    short8 qa1 = *(const short8*)(qbase + 32);

    const f32x4 zero = (f32x4){0.f, 0.f, 0.f, 0.f};
    f32x4 O[4];
    #pragma unroll
    for (int j = 0; j < 4; ++j) O[j] = zero;
    float lacc[4] = {0.f, 0.f, 0.f, 0.f};

    const int skey = t >> 3;             // 0..63
    const int soff = (t & 7) * 8;        // 0..56
    const unsigned short* Ksrc =
        Kb + ((size_t)b * SEQ + c * KC + skey) * 64 + soff;
    const unsigned short* Vsrc =
        Vt + ((size_t)b * 64 + skey) * SEQ + c * KC + soff;

    unsigned short* P = &Plds[w][0][0];

    for (int kt = 0; kt < KC; kt += KT) {
        *(short8*)&Kl[skey][soff] = *(const short8*)(Ksrc + (size_t)kt * 64);
        *(short8*)&Vl[skey][soff] = *(const short8*)(Vsrc + kt);
        __syncthreads();

        f32x4 s[4];
        #pragma unroll
        for (int sub = 0; sub < 4; ++sub) {
            short8 kb0 = *(const short8*)&Kl[sub * 16 + ln][quad * 8];
            short8 kb1 = *(const short8*)&Kl[sub * 16 + ln][32 + quad * 8];
            s[sub] = MFMA16(qa0, kb0, zero);
            s[sub] = MFMA16(qa1, kb1, s[sub]);
        }

        #pragma unroll
        for (int r = 0; r < 4; ++r) {
            float p0 = __builtin_amdgcn_exp2f(s[0][r]);
            float p1 = __builtin_amdgcn_exp2f(s[1][r]);
            float p2 = __builtin_amdgcn_exp2f(s[2][r]);
            float p3 = __builtin_amdgcn_exp2f(s[3][r]);
            lacc[r] += (p0 + p1) + (p2 + p3);
            unsigned u01 = pk2(p0, p1);
            unsigned u23 = pk2(p2, p3);
            unsigned short* prow = P + (quad * 4 + r) * 72;
            prow[ln]      = (unsigned short)u01;
            prow[16 + ln] = (unsigned short)(u01 >> 16);
            prow[32 + ln] = (unsigned short)u23;
            prow[48 + ln] = (unsigned short)(u23 >> 16);
        }
        short8 pa0 = *(const short8*)&Plds[w][ln][quad * 8];
        short8 pa1 = *(const short8*)&Plds[w][ln][32 + quad * 8];

        #pragma unroll
        for (int j = 0; j < 4; ++j) {
            short8 vb0 = *(const short8*)&Vl[j * 16 + ln][quad * 8];
            short8 vb1 = *(const short8*)&Vl[j * 16 + ln][32 + quad * 8];
            O[j] = MFMA16(pa0, vb0, O[j]);
            O[j] = MFMA16(pa1, vb1, O[j]);
        }
        __syncthreads();
    }

    #pragma unroll
    for (int m = 1; m < 16; m <<= 1) {
        #pragma unroll
        for (int r = 0; r < 4; ++r) lacc[r] += __shfl_xor(lacc[r], m);
    }

    float* __restrict__ ob = Opart + ((size_t)c * ROWS_TOTAL + q0) * 64;
    #pragma unroll
    for (int j = 0; j < 4; ++j)
        #pragma unroll
        for (int r = 0; r < 4; ++r)
            ob[(size_t)(quad * 4 + r) * 64 + j * 16 + ln] = O[j][r];

    if (ln == 0) {
        #pragma unroll
        for (int r = 0; r < 4; ++r)
            lpart[(size_t)c * ROWS_TOTAL + q0 + quad * 4 + r] = lacc[r];
    }
}

// ---------------------------------------------------------------------------
// Kernel 3: combine k-split partials:  out = sum_c O_c / sum_c l_c
// ---------------------------------------------------------------------------
__global__ __launch_bounds__(256) void reduce_kernel(
    const float* __restrict__ Opart, const float* __restrict__ lpart,
    float* __restrict__ out)
{
    const int idx = blockIdx.x * 256 + threadIdx.x;   // [0, 8192*64)
    const int r   = idx >> 6;
    float osum = 0.f, lsum = 0.f;
    #pragma unroll
    for (int c = 0; c < KSPLIT; ++c) {
        osum += Opart[(size_t)c * ROWS_TOTAL * HEAD + idx];
        lsum += lpart[(size_t)c * ROWS_TOTAL + r];
    }
    out[idx] = osum / lsum;
}

// ---------------------------------------------------------------------------
extern "C" void kernel_launch(void* const* d_in, const int* in_sizes, int n_in,
                              void* d_out, int out_size, void* d_ws, size_t ws_size,
                              hipStream_t stream)
{
    const float* x  = (const float*)d_in[0];
    const float* Wq = (const float*)d_in[1];
    const float* bq = (const float*)d_in[2];
    const float* Wk = (const float*)d_in[3];
    const float* bk = (const float*)d_in[4];
    const float* Wv = (const float*)d_in[5];
    const float* bv = (const float*)d_in[6];
    float* out = (float*)d_out;

    char* ws = (char*)d_ws;
    unsigned short* Qb = (unsigned short*)ws;                       // 1 MB
    unsigned short* Kb = Qb + (size_t)ROWS_TOTAL * HEAD;            // 1 MB
    unsigned short* Vt = Kb + (size_t)ROWS_TOTAL * HEAD;            // 1 MB
    unsigned short* Wf = Vt + (size_t)ROWS_TOTAL * HEAD;            // 384 KB
    float* lpart = (float*)(Wf + (size_t)3 * HEAD * EMB);           // 256 KB
    float* Opart = lpart + (size_t)KSPLIT * ROWS_TOTAL;             // 16 MB

    wprep_kernel<<<dim3(16, 3), 256, 0, stream>>>(Wq, Wk, Wv, Wf);
    qkv_mfma<<<dim3(512), 512, 0, stream>>>(x, Wf, bq, bk, bv, Qb, Kb, Vt);
    attn_mfma<<<dim3(64, KSPLIT), 512, 0, stream>>>(Qb, Kb, Vt, Opart, lpart);
    reduce_kernel<<<dim3((ROWS_TOTAL * HEAD) / 256), 256, 0, stream>>>(Opart, lpart, out);
}